// Round 4
// baseline (732.265 us; speedup 1.0000x reference)
//
#include <hip/hip_runtime.h>
#include <cmath>

// WaterNet: NH=128, NG=32, NR=15, NT=730, NS=800
#define NHID 128
#define NSITE 800
#define NTIME 730
#define NRTAP 15
#define TB 16            // timesteps per fused batch
#define SPB 4            // sites per block
constexpr int NSH = NSITE * NHID;  // 102400

typedef _Float16 f16x8 __attribute__((ext_vector_type(8)));
typedef _Float16 f16x2 __attribute__((ext_vector_type(2)));
typedef float f32x4 __attribute__((ext_vector_type(4)));

__device__ __forceinline__ float tanh_fast(float x) {
    float e = __expf(2.0f * x);
    return 1.0f - 2.0f / (e + 1.0f);
}
__device__ __forceinline__ float sigmoid_fast(float x) {
    return 1.0f / (1.0f + __expf(-x));
}

// ---------------------------------------------------------------------------
// P0: convert fcT2_w (fp32 [256][384]) to fp16 in MFMA-staging layout:
//   w2s[K0][kg][col][e] , k = K0*32 + kg*8 + e   (f16x8-chunk per (kg,col))
// ---------------------------------------------------------------------------
__global__ void k_prep_w2h(const float* __restrict__ w2, _Float16* __restrict__ w2s)
{
    int idx = blockIdx.x * 256 + threadIdx.x;   // 256*384 = 98304
    if (idx >= 98304) return;
    int k = idx / 384, col = idx - k * 384;
    int K0 = k >> 5, kg = (k >> 3) & 3, e = k & 7;
    w2s[(size_t)K0 * 12288 + kg * 3072 + col * 8 + e] = (_Float16)w2[(size_t)k * 384 + col];
}

// ---------------------------------------------------------------------------
// A1: per-site layer-1 for all three heads.
// ---------------------------------------------------------------------------
__global__ void k_site_l1(const float* __restrict__ xc,
                          const float* __restrict__ w1W, const float* __restrict__ b1W,
                          const float* __restrict__ w1R, const float* __restrict__ b1R,
                          const float* __restrict__ w1T, const float* __restrict__ b1T,
                          float* __restrict__ h1w, float* __restrict__ h1r,
                          float* __restrict__ basec)
{
    __shared__ float xr[32];
    int s = blockIdx.x, j = threadIdx.x;
    if (j < 32) xr[j] = xc[s * 32 + j];
    __syncthreads();
    float aW = b1W[j], aR = b1R[j], aT = b1T[j];
#pragma unroll 8
    for (int k = 0; k < 32; ++k) {
        float xv = xr[k];
        aW = fmaf(xv, w1W[k * 256 + j], aW);
        aR = fmaf(xv, w1R[k * 256 + j], aR);
        aT = fmaf(xv, w1T[(6 + k) * 256 + j], aT);
    }
    h1w[s * 256 + j]   = tanh_fast(aW);
    h1r[s * 256 + j]   = tanh_fast(aR);
    basec[s * 256 + j] = aT;
}

// ---------------------------------------------------------------------------
// A2: static parameter head layer-2 + activations.
// ---------------------------------------------------------------------------
__global__ void k_whead(const float* __restrict__ h1w,
                        const float* __restrict__ w2, const float* __restrict__ b2,
                        float* __restrict__ params)
{
    __shared__ float h[8 * 256];
    int sBase = blockIdx.x * 8, g = blockIdx.y, tid = threadIdx.x;
    for (int p = tid; p < 2048; p += 128) h[p] = h1w[sBase * 256 + p];
    __syncthreads();
    float bias = b2[g * 128 + tid];
    float acc[8];
#pragma unroll
    for (int i = 0; i < 8; ++i) acc[i] = bias;
    for (int k = 0; k < 256; ++k) {
        float wv = w2[k * 896 + g * 128 + tid];
#pragma unroll
        for (int i = 0; i < 8; ++i) acc[i] = fmaf(h[i * 256 + k], wv, acc[i]);
    }
#pragma unroll
    for (int i = 0; i < 8; ++i) {
        float v = acc[i], o;
        if (g == 0 || g == 1 || g == 3)  o = sigmoid_fast(v);
        else if (g == 2)                 o = sigmoid_fast(v) * 0.1f;
        else if (g == 4)                 o = __expf(v) * 2.0f;
        else if (g == 5)                 o = fmaxf(v, 0.0f);
        else                             o = v;  // ga raw (softmax later)
        params[g * NSH + (sBase + i) * 128 + tid] = o;
    }
}

// ---------------------------------------------------------------------------
// A3: softmax of ga over the 128 hidden buckets, in place.
// ---------------------------------------------------------------------------
__global__ void k_softmax_ga(float* __restrict__ ga)
{
    int s = blockIdx.x, h = threadIdx.x;
    float v = ga[s * 128 + h];
    float m = v;
#pragma unroll
    for (int off = 32; off; off >>= 1) m = fmaxf(m, __shfl_xor(m, off));
    __shared__ float ra[2], rb[2];
    if ((h & 63) == 0) ra[h >> 6] = m;
    __syncthreads();
    m = fmaxf(ra[0], ra[1]);
    float e = __expf(v - m);
    float t = e;
#pragma unroll
    for (int off = 32; off; off >>= 1) t += __shfl_xor(t, off);
    if ((h & 63) == 0) rb[h >> 6] = t;
    __syncthreads();
    ga[s * 128 + h] = e / (rb[0] + rb[1]);
}

// ---------------------------------------------------------------------------
// A4: routing head layer-2, r = relu(.), stored as [NRTAP][NSITE*NHID]
// ---------------------------------------------------------------------------
__global__ void k_rhead(const float* __restrict__ h1r,
                        const float* __restrict__ w2, const float* __restrict__ b2,
                        float* __restrict__ rbuf)
{
    __shared__ float h[8 * 256];
    int sBase = blockIdx.x * 8, g = blockIdx.y, tid = threadIdx.x;
    for (int p = tid; p < 2048; p += 128) h[p] = h1r[sBase * 256 + p];
    __syncthreads();
    int c = g * 128 + tid;
    float bias = b2[c];
    float acc[8];
#pragma unroll
    for (int i = 0; i < 8; ++i) acc[i] = bias;
    for (int k = 0; k < 256; ++k) {
        float wv = w2[k * 1920 + c];
#pragma unroll
        for (int i = 0; i < 8; ++i) acc[i] = fmaf(h[i * 256 + k], wv, acc[i]);
    }
    int hh = c / 15, ii = c - hh * 15;
#pragma unroll
    for (int i = 0; i < 8; ++i)
        rbuf[ii * NSH + (sBase + i) * 128 + hh] = fmaxf(acc[i], 0.0f);
}

// ---------------------------------------------------------------------------
// FUSED: per block = 4 sites, all 730 timesteps in 46 batches of 16.
//   phase L1   : h1 = tanh(basec + x@w1[0:6])      -> LDS Ah (MFMA A layout)
//   phase GEMM : MFMA 64x384, B straight from L2 into MFMA-layout registers
//   phase EPI  : activations + forcing folding     -> LDS sio (fp16 x4)
//   phase SCAN : 16 reservoir steps + ga-FIR       -> out
// Scan state (Sf,Ss,Sg,f[15]) and all per-cell params live in registers for
// the whole kernel: the old state/fut/PBh HBM round-trips are gone.
// ---------------------------------------------------------------------------
__global__ __launch_bounds__(512, 2) void k_fused(
    const float* __restrict__ x, const float* __restrict__ w1T,
    const float* __restrict__ basec, const f16x8* __restrict__ w2B,
    const float* __restrict__ b2,
    const float* __restrict__ params, const float* __restrict__ rbuf,
    float* __restrict__ out)
{
    __shared__ f16x8 Ah[8][4][64];                // 32 KB  (A fragments)
    __shared__ float w1s[1536];                   // 6 KB   (w1 rows 0..5)
    __shared__ float bcs[SPB][256];               // 4 KB
    __shared__ float xt[64][6];                   // 1.5 KB
    __shared__ float pls[64], evs[64], pssv[64];  // 768 B
    __shared__ _Float16 sio[64][128][4];          // 64 KB  {pl, ev, vm, -}
    __shared__ float part[8][TB];                 // 512 B

    int tid = threadIdx.x;
    int s0 = blockIdx.x * SPB;

    // ---- one-time init ----
    for (int i = tid; i < 1536; i += 512) w1s[i] = w1T[i];
    for (int i = tid; i < SPB * 256; i += 512)
        bcs[i >> 8][i & 255] = basec[(size_t)(s0 + (i >> 8)) * 256 + (i & 255)];

    // scan cell ownership: thread -> (site sl, bucket h)
    int slc = tid >> 7, hc = tid & 127;
    int cell = (s0 + slc) * 128 + hc;
    float kp  = params[0 * NSH + cell];
    float ksP = params[1 * NSH + cell];
    float kgP = params[2 * NSH + cell];
    float gp  = params[3 * NSH + cell];
    float gL  = params[4 * NSH + cell];
    float qb  = params[5 * NSH + cell];
    float ga  = params[6 * NSH + cell];
    float kq  = ksP * (1.0f - gp);
    float wr[NRTAP];
#pragma unroll
    for (int i = 0; i < NRTAP; ++i) wr[i] = ga * rbuf[i * NSH + cell];
    float Sf = 0.0f, Ss = 0.0f, Sg = 0.0f, f[NRTAP];
#pragma unroll
    for (int i = 0; i < NRTAP; ++i) f[i] = 0.0f;

    // GEMM ids: 8 waves, wave w owns cols [w*48, w*48+48)
    int wid = tid >> 6, lane = tid & 63;
    int l15 = lane & 15, l4 = lane >> 4;
    int n0w = wid * 48;
    float bbias[3];
#pragma unroll
    for (int nf = 0; nf < 3; ++nf) bbias[nf] = b2[n0w + nf * 16 + l15];

    // L1 ids: thread -> cols j0..j0+7 for rows rg*4..rg*4+3
    int jg = tid & 31, rg = tid >> 5;
    int j0 = jg * 8;
    int ksw = jg >> 2, kgw = jg & 3;

    const int NB = (NTIME + TB - 1) / TB;   // 46
    for (int b = 0; b < NB; ++b) {
        int t0g = b * TB;
        int nst = NTIME - t0g; if (nst > TB) nst = TB;

        // prefetch B fragments for ks=0 (straight into MFMA layout)
        f16x8 bf[3], bfn[3];
#pragma unroll
        for (int nf = 0; nf < 3; ++nf)
            bf[nf] = w2B[(size_t)l4 * 384 + n0w + nf * 16 + l15];

        // stage x rows + snow-fraction scalars (row = sl*16 + tloc)
        if (tid < 64) {
            int r = tid, sl = r >> 4, tl = r & 15;
            int t = t0g + tl;
            bool ok = t < NTIME;
            int tt = ok ? t : (NTIME - 1);
            const float* xp = &x[((size_t)tt * 800 + s0 + sl) * 6];
            float P = xp[0], E = xp[1], T1 = xp[2], T2 = xp[3];
            xt[r][0] = P; xt[r][1] = E; xt[r][2] = T1;
            xt[r][3] = T2; xt[r][4] = xp[4]; xt[r][5] = xp[5];
            float den = T2 - T1;
            float cf = (T1 + T2) / ((den == 0.0f) ? 1.0f : den);
            cf = fminf(fmaxf(cf, -0.999999f), 0.999999f);
            float vf = acosf(cf) * (1.0f / 3.1415f);
            vf = (T1 >= 0.0f) ? 0.0f : vf;
            vf = (T2 <= 0.0f) ? 1.0f : vf;
            pls[r]  = ok ? P * (1.0f - vf) : 0.0f;
            evs[r]  = ok ? E : 0.0f;
            pssv[r] = ok ? P * vf : 0.0f;
        }
        __syncthreads();   // B1: xt ready; Ah free (prev GEMM done), sio free

        // ---- L1: 4 rows x 8 cols per thread -> Ah ----
        {
            float w1c[6][8];
#pragma unroll
            for (int c = 0; c < 6; ++c) {
                float4 lo = *(const float4*)&w1s[c * 256 + j0];
                float4 hi = *(const float4*)&w1s[c * 256 + j0 + 4];
                w1c[c][0] = lo.x; w1c[c][1] = lo.y; w1c[c][2] = lo.z; w1c[c][3] = lo.w;
                w1c[c][4] = hi.x; w1c[c][5] = hi.y; w1c[c][6] = hi.z; w1c[c][7] = hi.w;
            }
#pragma unroll
            for (int rr = 0; rr < 4; ++rr) {
                int r = rg * 4 + rr, sl = r >> 4;
                const float* bp = &bcs[sl][j0];
                float4 b0 = *(const float4*)bp;
                float4 b1 = *(const float4*)(bp + 4);
                float a[8] = {b0.x, b0.y, b0.z, b0.w, b1.x, b1.y, b1.z, b1.w};
#pragma unroll
                for (int c = 0; c < 6; ++c) {
                    float xv = xt[r][c];
#pragma unroll
                    for (int e = 0; e < 8; ++e) a[e] = fmaf(xv, w1c[c][e], a[e]);
                }
                f16x8 hv;
#pragma unroll
                for (int e = 0; e < 8; ++e) hv[e] = (_Float16)tanh_fast(a[e]);
                Ah[ksw][kgw][r] = hv;
            }
        }
        __syncthreads();   // B2: Ah ready

        // ---- GEMM: 8 ks, B register-streamed, no barriers ----
        f32x4 acc[4][3];
#pragma unroll
        for (int nf = 0; nf < 3; ++nf) {
            float bb = bbias[nf];
#pragma unroll
            for (int mf = 0; mf < 4; ++mf) acc[mf][nf] = (f32x4){bb, bb, bb, bb};
        }
        for (int ks = 0; ks < 8; ++ks) {
            if (ks < 7) {
#pragma unroll
                for (int nf = 0; nf < 3; ++nf)
                    bfn[nf] = w2B[(size_t)(ks + 1) * 1536 + l4 * 384 + n0w + nf * 16 + l15];
            }
            f16x8 af[4];
#pragma unroll
            for (int mf = 0; mf < 4; ++mf) af[mf] = Ah[ks][l4][mf * 16 + l15];
#pragma unroll
            for (int mf = 0; mf < 4; ++mf)
#pragma unroll
                for (int nf = 0; nf < 3; ++nf)
                    acc[mf][nf] = __builtin_amdgcn_mfma_f32_16x16x32_f16(
                        af[mf], bf[nf], acc[mf][nf], 0, 0, 0);
#pragma unroll
            for (int nf = 0; nf < 3; ++nf) bf[nf] = bfn[nf];
        }

        // ---- epilogue: activations -> sio (fp16) ----
#pragma unroll
        for (int mf = 0; mf < 4; ++mf) {
#pragma unroll
            for (int nf = 0; nf < 3; ++nf) {
                int colg = n0w + nf * 16 + l15;
                int ch = colg >> 7, cl = colg & 127;
#pragma unroll
                for (int rr = 0; rr < 4; ++rr) {
                    int rl = mf * 16 + l4 * 4 + rr;
                    float v = acc[mf][nf][rr];
                    float o;
                    if (ch == 0)
                        o = pls[rl] * fminf(fmaxf(v * (1.0f / 3.0f) + 0.5f, 0.0f), 1.0f);
                    else if (ch == 1)
                        o = evs[rl] * fmaxf(v, 0.0f) * 2.0f;
                    else
                        o = fminf(__expf(v), 60000.0f);
                    sio[rl][cl][ch] = (_Float16)o;
                }
            }
        }
        __syncthreads();   // B3: sio ready

        // ---- scan: 16 steps (static unroll, uniform guard) ----
#pragma unroll
        for (int t = 0; t < TB; ++t) {
            if (t < nst) {
                union { unsigned u[2]; f16x2 h[2]; uint2 v; } pk;
                pk.v = *(const uint2*)&sio[slc * 16 + t][hc][0];
                float pl = (float)pk.h[0].x;
                float ev = (float)pk.h[0].y;
                float vm = (float)pk.h[1].x;
                float ps = pssv[slc * 16 + t];

                float x1 = Sf + ps;
                float qf = fminf(x1, vm);
                Sf = fmaxf(x1 - vm, 0.0f);
                float H  = fmaxf(Ss + pl + qf - ev, 0.0f);
                float qp = fmaxf(kp * (H - gL), 0.0f);
                float mh = fminf(H, gL);
                float qs = ksP * mh;
                Ss = H - qp - qs;
                float qg = fmaf(kgP, fmaf(qs, gp, Sg), qb);
                Sg = Sg - qg;
                float qt = qp + kq * mh + qg;

#pragma unroll
                for (int j = 0; j < NRTAP; ++j) f[j] = fmaf(wr[j], qt, f[j]);
                float c = f[0];
#pragma unroll
                for (int j = 0; j < NRTAP - 1; ++j) f[j] = f[j + 1];
                f[NRTAP - 1] = 0.0f;

#pragma unroll
                for (int off = 32; off; off >>= 1) c += __shfl_xor(c, off);
                if (lane == 0) part[wid][t] = c;
            }
        }
        __syncthreads();   // B4: part ready, sio reads done

        if (tid < 64) {
            int sl = tid >> 4, t = tid & 15;
            if (t < nst)
                out[(size_t)(t0g + t) * 800 + s0 + sl] =
                    part[sl * 2][t] + part[sl * 2 + 1][t];
        }
    }
}

// ---------------------------------------------------------------------------
extern "C" void kernel_launch(void* const* d_in, const int* in_sizes, int n_in,
                              void* d_out, int out_size, void* d_ws, size_t ws_size,
                              hipStream_t stream)
{
    const float* x      = (const float*)d_in[0];
    const float* xc     = (const float*)d_in[1];
    const float* fcW1_w = (const float*)d_in[2];
    const float* fcW1_b = (const float*)d_in[3];
    const float* fcW2_w = (const float*)d_in[4];
    const float* fcW2_b = (const float*)d_in[5];
    const float* fcT1_w = (const float*)d_in[6];
    const float* fcT1_b = (const float*)d_in[7];
    const float* fcT2_w = (const float*)d_in[8];
    const float* fcT2_b = (const float*)d_in[9];
    const float* fcR1_w = (const float*)d_in[10];
    const float* fcR1_b = (const float*)d_in[11];
    const float* fcR2_w = (const float*)d_in[12];
    const float* fcR2_b = (const float*)d_in[13];
    float* out = (float*)d_out;

    float* ws = (float*)d_ws;
    size_t off = 0;
    float* params = ws + off; off += (size_t)7 * NSH;      // 716800
    float* rbuf   = ws + off; off += (size_t)NRTAP * NSH;  // 1536000
    float* basec  = ws + off; off += 800 * 256;
    float* h1w    = ws + off; off += 800 * 256;
    float* h1r    = ws + off; off += 800 * 256;
    _Float16* w2s = (_Float16*)(ws + off); off += 49152;   // 98304 fp16

    k_prep_w2h<<<384, 256, 0, stream>>>(fcT2_w, w2s);
    k_site_l1<<<800, 256, 0, stream>>>(xc, fcW1_w, fcW1_b, fcR1_w, fcR1_b,
                                       fcT1_w, fcT1_b, h1w, h1r, basec);
    k_whead<<<dim3(100, 7), 128, 0, stream>>>(h1w, fcW2_w, fcW2_b, params);
    k_softmax_ga<<<800, 128, 0, stream>>>(params + (size_t)6 * NSH);
    k_rhead<<<dim3(100, 15), 128, 0, stream>>>(h1r, fcR2_w, fcR2_b, rbuf);

    k_fused<<<NSITE / SPB, 512, 0, stream>>>(
        x, fcT1_w, basec, (const f16x8*)w2s, fcT2_b, params, rbuf, out);
}